// Round 3
// baseline (609.077 us; speedup 1.0000x reference)
//
#include <hip/hip_runtime.h>
#include <hip/hip_bf16.h>

// ---------------------------------------------------------------------------
// EncoderLayer on MI355X (gfx950), round 8.
// Mainloop rework vs R7: K-tile=32, 4-slot LDS ring (128KB), depth-3 tile
// prefetch, ONE counted vmcnt gate per K-tile (vmcnt(8) steady -> 4 -> 0),
// 2 phases/tile each [6 ds_read | 2 gl_lds | barrier | 8 MFMA | barrier].
// Per-wave output 128x64 contiguous (acc[4][2]). Epilogues reindexed.
// Attention / LN / prep unchanged.
// ---------------------------------------------------------------------------

#define DM    1024
#define DFF   4096
#define NH    16
#define HD    64
#define BATCH 4
#define SEQ   2048
#define TOK   (BATCH * SEQ)   // 8192

typedef __attribute__((ext_vector_type(8))) __bf16 bf16x8;
typedef __attribute__((ext_vector_type(4))) float f32x4;
typedef __attribute__((ext_vector_type(16))) float f32x16;
typedef __attribute__((ext_vector_type(4))) unsigned short u16x4;

typedef const __attribute__((address_space(1))) unsigned int* gas1_t;
typedef __attribute__((address_space(3))) unsigned int* las3_t;

__device__ __forceinline__ void gl_lds16(const void* g, void* l) {
  // async global->LDS, 16B per lane; LDS dest = wave-uniform base + lane*16
  __builtin_amdgcn_global_load_lds((gas1_t)g, (las3_t)l, 16, 0, 0);
}

__device__ __forceinline__ unsigned short f2bu(float x) {
  return __builtin_bit_cast(unsigned short, __float2bfloat16(x));
}

// pack hi16(a),hi16(b) -> (b | a<<16): bf16 truncation of two floats, 1 instr
__device__ __forceinline__ unsigned pk_bf16_trunc(float hi, float lo) {
  return __builtin_amdgcn_perm(__builtin_bit_cast(unsigned, hi),
                               __builtin_bit_cast(unsigned, lo), 0x07060302u);
}

// ---------------------------------------------------------------------------
// cast fp32 -> bf16 (vectorized x4)
// ---------------------------------------------------------------------------
__global__ __launch_bounds__(256) void cast_bf16(
    const float* __restrict__ in, unsigned short* __restrict__ out, int n4) {
  int i = blockIdx.x * 256 + threadIdx.x;
  if (i >= n4) return;
  float4 v = ((const float4*)in)[i];
  u16x4 o = {f2bu(v.x), f2bu(v.y), f2bu(v.z), f2bu(v.w)};
  ((u16x4*)out)[i] = o;
}

// ---------------------------------------------------------------------------
// out[n][k] = bf16(in[k][n])   (LDS-tiled transpose, block (32,8))
// ---------------------------------------------------------------------------
__global__ __launch_bounds__(256) void transpose_cast(
    const float* __restrict__ in, unsigned short* __restrict__ out, int K, int N) {
  __shared__ float tile[32][33];
  int n0 = blockIdx.x * 32, k0 = blockIdx.y * 32;
  int tx = threadIdx.x, ty = threadIdx.y;
#pragma unroll
  for (int i = 0; i < 4; ++i)
    tile[ty + 8 * i][tx] = in[(size_t)(k0 + ty + 8 * i) * N + n0 + tx];
  __syncthreads();
#pragma unroll
  for (int i = 0; i < 4; ++i)
    out[(size_t)(n0 + ty + 8 * i) * K + k0 + tx] = f2bu(tile[tx][ty + 8 * i]);
}

// 4 square (1024x1024) weight transposes in one launch (z selects matrix)
__global__ __launch_bounds__(256) void transpose_cast4(
    const float* __restrict__ A0, const float* __restrict__ A1,
    const float* __restrict__ A2, const float* __restrict__ A3,
    unsigned short* __restrict__ O0, unsigned short* __restrict__ O1,
    unsigned short* __restrict__ O2, unsigned short* __restrict__ O3) {
  __shared__ float tile[32][33];
  const float* in; unsigned short* out;
  switch (blockIdx.z) {
    case 0: in = A0; out = O0; break;
    case 1: in = A1; out = O1; break;
    case 2: in = A2; out = O2; break;
    default: in = A3; out = O3; break;
  }
  int n0 = blockIdx.x * 32, k0 = blockIdx.y * 32;
  int tx = threadIdx.x, ty = threadIdx.y;
#pragma unroll
  for (int i = 0; i < 4; ++i)
    tile[ty + 8 * i][tx] = in[(size_t)(k0 + ty + 8 * i) * DM + n0 + tx];
  __syncthreads();
#pragma unroll
  for (int i = 0; i < 4; ++i)
    out[(size_t)(n0 + ty + 8 * i) * DM + k0 + tx] = f2bu(tile[tx][ty + 8 * i]);
}

// ---------------------------------------------------------------------------
// 256x256 GEMM mainloop, K-tile=32, 4-slot LDS ring, depth-3 prefetch.
//   8 waves: wr=w>>2 (2, rows wr*128..+128), wc=w&3 (4, cols wc*64..+64).
//   LDS slot (A or B) = [256 rows][32 k] bf16 = 16KB; rows 64B; 16B chunk c
//   of row r stored at c ^ ((r>>1)&3); global source pre-swizzled to match.
//   Staging per tile: A = 2 gl_lds/wave (rowhalves), B same. Stage tile t+3
//   (slot (t+3)&3) during tile t (A at ph0, B at ph1).
//   Tile t: ph ks=0: [rd A(4)+B(2) slot t&3 | stage A | barrier | 8 MFMA |
//   barrier]; ks=1: [rd | stage B | barrier | 8 MFMA | GATE].
//   GATE (end of tile) = s_waitcnt vmcnt(8) + s_barrier: retires tile t+1's
//   4 loads (stage-to-gate distance ~6 phases); never drains in main loop.
// ---------------------------------------------------------------------------
__device__ __forceinline__ void mainloop256(
    const unsigned short* __restrict__ A, int lda,
    const unsigned short* __restrict__ Bt, int ldb, int Kl,
    int m0, int n0, unsigned short* As, unsigned short* Bs,
    f32x16 acc[4][2]) {
  const int tid = threadIdx.x, lane = tid & 63, w = tid >> 6;
  const int l31 = lane & 31, khalf = lane >> 5;
  const int wr = w >> 2, wc = w & 3;

  // staging source: instr i (rowhalf): row = i*128 + w*16 + (lane>>2),
  // lds chunk = lane&3, source chunk = (lane&3) ^ ((row>>1)&3)
  const unsigned short* pa[2];
  const unsigned short* pb[2];
#pragma unroll
  for (int i = 0; i < 2; ++i) {
    const int row = i * 128 + w * 16 + (lane >> 2);
    const int cs = ((lane & 3) ^ ((row >> 1) & 3)) * 8;
    pa[i] = A + (size_t)(m0 + row) * lda + cs;
    pb[i] = Bt + (size_t)(n0 + row) * ldb + cs;
  }

  bf16x8 aF[4], bF[2];

#define STAGE_A(SS)                                                           \
  { gl_lds16(pa[0], (char*)As + (SS) * 16384 + w * 1024);                     \
    gl_lds16(pa[1], (char*)As + (SS) * 16384 + 8192 + w * 1024);              \
    pa[0] += 32; pa[1] += 32; }
#define STAGE_B(SS)                                                           \
  { gl_lds16(pb[0], (char*)Bs + (SS) * 16384 + w * 1024);                     \
    gl_lds16(pb[1], (char*)Bs + (SS) * 16384 + 8192 + w * 1024);              \
    pb[0] += 32; pb[1] += 32; }

#define RD_PH(SLOT, KS)                                                       \
  { const char* Ab = (const char*)As + (SLOT) * 16384;                        \
    const char* Bb = (const char*)Bs + (SLOT) * 16384;                        \
    _Pragma("unroll") for (int rt = 0; rt < 4; ++rt) {                        \
      const int row = wr * 128 + rt * 32 + l31;                               \
      aF[rt] = *(const bf16x8*)(Ab + row * 64 +                               \
                  ((((KS) * 2 + khalf) ^ ((row >> 1) & 3)) << 4));            \
    }                                                                         \
    _Pragma("unroll") for (int ni = 0; ni < 2; ++ni) {                        \
      const int brow = wc * 64 + ni * 32 + l31;                               \
      bF[ni] = *(const bf16x8*)(Bb + brow * 64 +                              \
                  ((((KS) * 2 + khalf) ^ ((brow >> 1) & 3)) << 4));           \
    } }

#define MMA_PH()                                                              \
  { __builtin_amdgcn_s_setprio(1);                                            \
    _Pragma("unroll") for (int rt = 0; rt < 4; ++rt)                          \
      _Pragma("unroll") for (int ni = 0; ni < 2; ++ni)                        \
        acc[rt][ni] = __builtin_amdgcn_mfma_f32_32x32x16_bf16(                \
            aF[rt], bF[ni], acc[rt][ni], 0, 0, 0);                            \
    __builtin_amdgcn_s_setprio(0); }

// TILE: SLOT = t&3, SS = (t+3)&3, STG literal 0/1, GATESTR at tile end.
#define TILE(SLOT, SS, STG, GATESTR)                                          \
  RD_PH(SLOT, 0);                                                             \
  if (STG) STAGE_A(SS);                                                       \
  asm volatile("s_barrier" ::: "memory");                                     \
  MMA_PH();                                                                   \
  asm volatile("s_barrier" ::: "memory");                                     \
  RD_PH(SLOT, 1);                                                             \
  if (STG) STAGE_B(SS);                                                       \
  asm volatile("s_barrier" ::: "memory");                                     \
  MMA_PH();                                                                   \
  asm volatile(GATESTR ::: "memory");

#define GATE8 "s_waitcnt vmcnt(8)\n\ts_barrier"
#define GATE4 "s_waitcnt vmcnt(4)\n\ts_barrier"
#define GATE0 "s_waitcnt vmcnt(0)\n\ts_barrier"

  // prologue: stage tiles 0,1,2 (A,B interleaved per tile -> retirement
  // order A(t),B(t)); gate retires tile 0 -> vmcnt(8)
  STAGE_A(0); STAGE_B(0);
  STAGE_A(1); STAGE_B(1);
  STAGE_A(2); STAGE_B(2);
  asm volatile(GATE8 ::: "memory");

  const int NT = Kl >> 5;  // K-tiles of 32; NT multiple of 4, >= 8
  for (int t = 0; t < NT - 4; t += 4) {
    TILE(0, 3, 1, GATE8);
    TILE(1, 0, 1, GATE8);
    TILE(2, 1, 1, GATE8);
    TILE(3, 2, 1, GATE8);
  }
  TILE(0, 3, 1, GATE8);   // tile NT-4: stages tile NT-1; gate retires NT-3
  TILE(1, 0, 0, GATE4);   // tile NT-3: gate retires NT-2
  TILE(2, 1, 0, GATE0);   // tile NT-2: gate retires NT-1
  TILE(3, 2, 0, "");      // tile NT-1: nothing outstanding

#undef GATE0
#undef GATE4
#undef GATE8
#undef TILE
#undef MMA_PH
#undef RD_PH
#undef STAGE_B
#undef STAGE_A
}

// C/D layout (32x32): col = lane&31, row = (reg&3) + 8*(reg>>2) + 4*(lane>>5)
// acc[rt][ni]: rows m0+wr*128+rt*32, cols n0+wc*64+ni*32

// XCD-aware block swizzle: blocks with equal (lin%8) land on one XCD; give
// each XCD a contiguous chunk. Requires gridDim.x*gridDim.y % 8 == 0.
__device__ __forceinline__ void xcd_swizzle(int& bx, int& by) {
  const int gx = gridDim.x, nxy = gx * gridDim.y;
  int lin = by * gx + bx;
  lin = (lin & 7) * (nxy >> 3) + (lin >> 3);
  bx = lin % gx;
  by = lin / gx;
}

// ---------------------------------------------------------------------------
// Generic C[M,N] = epi(A @ Bt^T + bias).  gridDim.z=2 -> split-K: block z
// computes K-slice [z*Kl, (z+1)*Kl) into C0/C1 (bias only in z=0).
// ---------------------------------------------------------------------------
__global__ __launch_bounds__(512, 2) void gemm256(
    const unsigned short* __restrict__ A, int lda,
    const unsigned short* __restrict__ Bt, int ldb, int Kl,
    const float* __restrict__ bias, void* __restrict__ C0,
    void* __restrict__ C1, int N, float alpha, int relu, int ofp32) {
  __shared__ unsigned short As[32768];
  __shared__ unsigned short Bs[32768];
  const int tid = threadIdx.x, lane = tid & 63, w = tid >> 6;
  const int l31 = lane & 31, khalf = lane >> 5;
  const int wr = w >> 2, wc = w & 3;
  int bx = blockIdx.x, by = blockIdx.y;
  xcd_swizzle(bx, by);
  const int m0 = by * 256, n0 = bx * 256;
  const int koff = blockIdx.z * Kl;
  void* Cout = blockIdx.z ? C1 : C0;
  const float* be = blockIdx.z ? nullptr : bias;

  f32x16 acc[4][2];
#pragma unroll
  for (int rt = 0; rt < 4; ++rt)
#pragma unroll
    for (int ni = 0; ni < 2; ++ni)
#pragma unroll
      for (int r = 0; r < 16; ++r) acc[rt][ni][r] = 0.f;

  mainloop256(A + koff, lda, Bt + koff, ldb, Kl, m0, n0, As, Bs, acc);

#pragma unroll
  for (int ni = 0; ni < 2; ++ni) {
    const int col = n0 + wc * 64 + ni * 32 + l31;
    const float bvv = be ? be[col] : 0.f;
#pragma unroll
    for (int rt = 0; rt < 4; ++rt) {
#pragma unroll
      for (int g = 0; g < 4; ++g) {
        const int rbase = m0 + wr * 128 + rt * 32 + g * 8 + khalf * 4;
#pragma unroll
        for (int r = 0; r < 4; ++r) {
          float val = alpha * (acc[rt][ni][g * 4 + r] + bvv);
          if (relu) val = fmaxf(val, 0.f);
          size_t idx = (size_t)(rbase + r) * N + col;
          if (ofp32) ((float*)Cout)[idx] = val;
          else ((unsigned short*)Cout)[idx] = f2bu(val);
        }
      }
    }
  }
}

// ---------------------------------------------------------------------------
// Fused QKV gemm (256x256). N=3072: region 0: Q * QSCALE -> Qb; 1: K -> Kb;
// 2: V -> Vtg transposed per head [(b*16+h)*64+d][s].
// ---------------------------------------------------------------------------
#define QSCALE 0.18033688f  // (1/sqrt(64)) * log2(e): softmax runs in exp2 domain

__global__ __launch_bounds__(512, 2) void gemm_qkv256(
    const unsigned short* __restrict__ A, const unsigned short* __restrict__ Bt,
    const float* __restrict__ bq, const float* __restrict__ bk,
    const float* __restrict__ bv,
    unsigned short* __restrict__ Qb, unsigned short* __restrict__ Kb,
    unsigned short* __restrict__ Vtg) {
  __shared__ unsigned short As[32768];
  __shared__ unsigned short Bs[32768];
  const int tid = threadIdx.x, lane = tid & 63, w = tid >> 6;
  const int l31 = lane & 31, khalf = lane >> 5;
  const int wr = w >> 2, wc = w & 3;
  int bx = blockIdx.x, by = blockIdx.y;
  xcd_swizzle(bx, by);
  const int m0 = by * 256, n0 = bx * 256;

  f32x16 acc[4][2];
#pragma unroll
  for (int rt = 0; rt < 4; ++rt)
#pragma unroll
    for (int ni = 0; ni < 2; ++ni)
#pragma unroll
      for (int r = 0; r < 16; ++r) acc[rt][ni][r] = 0.f;

  mainloop256(A, DM, Bt, DM, DM, m0, n0, As, Bs, acc);

  const int region = n0 >> 10;  // 0=Q 1=K 2=V (256-tiles never straddle)
  if (region < 2) {
    unsigned short* Out = region ? Kb : Qb;
    const float* bias = region ? bk : bq;
    const float alpha = region ? 1.0f : QSCALE;
#pragma unroll
    for (int ni = 0; ni < 2; ++ni) {
      const int col = (n0 & 1023) + wc * 64 + ni * 32 + l31;
      const float bvv = bias[col];
#pragma unroll
      for (int rt = 0; rt < 4; ++rt) {
#pragma unroll
        for (int g = 0; g < 4; ++g) {
          const int rbase = m0 + wr * 128 + rt * 32 + g * 8 + khalf * 4;
#pragma unroll
          for (int r = 0; r < 4; ++r)
            Out[(size_t)(rbase + r) * DM + col] =
                f2bu(alpha * (acc[rt][ni][g * 4 + r] + bvv));
        }
      }
    }
  } else {
#pragma unroll
    for (int ni = 0; ni < 2; ++ni) {
      const int col = (n0 & 1023) + wc * 64 + ni * 32 + l31;  // d_model idx
      const float bvv = bv[col];
      const int hh = col >> 6, dl = col & 63;
#pragma unroll
      for (int rt = 0; rt < 4; ++rt) {
#pragma unroll
        for (int g = 0; g < 4; ++g) {
          const int sbase = m0 + wr * 128 + rt * 32 + g * 8 + khalf * 4;
          const int b_ = sbase >> 11, s0 = sbase & 2047;
          u16x4 pk;
#pragma unroll
          for (int r = 0; r < 4; ++r)
            pk[r] = f2bu(acc[rt][ni][g * 4 + r] + bvv);
          *(u16x4*)(Vtg + ((size_t)((b_ * NH + hh) * HD + dl)) * SEQ + s0) = pk;
        }
      }
    }
  }
}

// ---------------------------------------------------------------------------
// Flash attention, S^T formulation, BQ=128, NO-max exp2 softmax. (unchanged)
// ---------------------------------------------------------------------------
__global__ __launch_bounds__(256) void attn_kernel(
    const unsigned short* __restrict__ Q, const unsigned short* __restrict__ K,
    const unsigned short* __restrict__ Vtg, unsigned short* __restrict__ O) {
  __shared__ unsigned short Kt[2][64 * 64];   // [kv][d] swizzled, 8KB x2
  __shared__ unsigned short Vt[2][64 * 64];   // [d][kv] swizzled, 8KB x2
  __shared__ unsigned short Pt[4][32 * 64];   // per-wave [q][kv], 4KB x4
  __shared__ __align__(16) float redL[4][32];

  const int tid = threadIdx.x, lane = tid & 63, w = tid >> 6;
  const int l15 = lane & 15, quad = lane >> 4;
  const int q0 = blockIdx.x * 128;
  const int bh = blockIdx.y, b = bh >> 4, hh = bh & 15;
  const size_t tokbase = (size_t)b * SEQ;

  bf16x8 qf[2][2];
#pragma unroll
  for (int qg = 0; qg < 2; ++qg)
#pragma unroll
    for (int kk = 0; kk < 2; ++kk)
      qf[qg][kk] = *(const bf16x8*)(Q +
          (tokbase + q0 + w * 32 + qg * 16 + l15) * DM + hh * HD + kk * 32 + quad * 8);

  float l_run[2] = {0.f, 0.f};
  f32x4 Oacc[2][4];
#pragma unroll
  for (int qg = 0; qg < 2; ++qg)
#pragma unroll
    for (int nt = 0; nt < 4; ++nt) Oacc[qg][nt] = {0.f, 0.f, 0.f, 0.f};

  char* ptw = (char*)&Pt[w][0];

  int rowS[2], csrcS[2];
#pragma unroll
  for (int i = 0; i < 2; ++i) {
    int f = (i * 4 + w) * 64 + lane;
    rowS[i] = f >> 3;
    csrcS[i] = ((f & 7) ^ (rowS[i] & 7)) * 8;
  }
  const unsigned short* kg[2];
  const unsigned short* vg[2];
  char* ldsK[2][2]; char* ldsV[2][2];
#pragma unroll
  for (int i = 0; i < 2; ++i) {
    kg[i] = K + (tokbase + rowS[i]) * DM + hh * HD + csrcS[i];
    vg[i] = Vtg + ((size_t)bh * HD + rowS[i]) * SEQ + csrcS[i];
#pragma unroll
    for (int bb = 0; bb < 2; ++bb) {
      ldsK[bb][i] = (char*)Kt[bb] + (size_t)((i * 4 + w) * 1024);
      ldsV[bb][i] = (char*)Vt[bb] + (size_t)((i * 4 + w) * 1024);
    }
  }

#pragma unroll
  for (int i = 0; i < 2; ++i) {
    gl_lds16(kg[i], ldsK[0][i]);
    gl_lds16(vg[i], ldsV[0][i]);
    kg[i] += 64 * DM;
    vg[i] += 64;
  }

  for (int j = 0; j < SEQ / 64; ++j) {
    const int buf = j & 1;
    __syncthreads();
    if (j + 1 < SEQ / 64) {
#pragma unroll
      for (int i = 0; i < 2; ++i) {
        gl_lds16(kg[i], ldsK[buf ^ 1][i]);
        gl_lds16(vg[i], ldsV[buf ^ 1][i]);
        kg[i] += 64 * DM;
        vg[i] += 64;
      }
    }

    const char* ktb = (const char*)Kt[buf];
    const char* vtb = (const char*)Vt[buf];

    f32x4 S[2][4];
#pragma unroll
    for (int qg = 0; qg < 2; ++qg)
#pragma unroll
      for (int mt = 0; mt < 4; ++mt) S[qg][mt] = {0.f, 0.f, 0.f, 0.f};
#pragma unroll
    for (int kk = 0; kk < 2; ++kk) {
#pragma unroll
      for (int mt = 0; mt < 4; ++mt) {
        bf16x8 aK = *(const bf16x8*)(ktb + (mt * 16 + l15) * 128 +
                                     (((kk * 4 + quad) ^ (l15 & 7)) * 16));
        S[0][mt] = __builtin_amdgcn_mfma_f32_16x16x32_bf16(aK, qf[0][kk], S[0][mt], 0, 0, 0);
        S[1][mt] = __builtin_amdgcn_mfma_f32_16x16x32_bf16(aK, qf[1][kk], S[1][mt], 0, 0, 0);
      }
    }

#pragma unroll
    for (int qg = 0; qg < 2; ++qg) {
      float rs = 0.f;
#pragma unroll
      for (int mt = 0; mt < 4; ++mt) {
        float p0 = __builtin_amdgcn_exp2f(S[qg][mt][0]);
        float p1 = __builtin_amdgcn_exp2f(S[qg][mt][1]);
        float p2 = __builtin_amdgcn_exp2f(S[qg][mt][2]);
        float p3 = __builtin_amdgcn_exp2f(S[qg][mt][3]);
        rs += (p0 + p1) + (p2 + p3);
        uint2 pk = {pk_bf16_trunc(p1, p0), pk_bf16_trunc(p3, p2)};
        *(uint2*)(ptw + (qg * 16 + l15) * 128 +
                  (((mt * 2 + (quad >> 1)) ^ (l15 & 7)) * 16 + (quad & 1) * 8)) = pk;
      }
      l_run[qg] += rs;
    }

#pragma unroll
    for (int kk = 0; kk < 2; ++kk) {
      bf16x8 aP[2];
#pragma unroll
      for (int qg = 0; qg < 2; ++qg)
        aP[qg] = *(const bf16x8*)(ptw + (qg * 16 + l15) * 128 +
                                  (((kk * 4 + quad) ^ (l15 & 7)) * 16));
#pragma unroll
      for (int nt = 0; nt < 4; ++nt) {
        bf16x8 bV = *(const bf16x8*)(vtb + (nt * 16 + l15) * 128 +
                                     (((kk * 4 + quad) ^ (l15 & 7)) * 16));
        Oacc[0][nt] = __builtin_amdgcn_mfma_f32_16x16x32_bf16(aP[0], bV, Oacc[0][nt], 0, 0, 0);
        Oacc[1][nt] = __builtin_amdgcn_mfma_f32_16x16x32_bf16(aP[1], bV, Oacc[1][nt], 0, 0, 0);
      }
    }
  }

#pragma unroll
  for (int qg = 0; qg < 2; ++qg) {
    l_run[qg] += __shfl_xor(l_run[qg], 16);
    l_run[qg] += __shfl_xor(l_run[qg], 32);
    if (lane < 16) redL[w][qg * 16 + l15] = l_run[qg];
  }
#pragma unroll
  for (int qg = 0; qg < 2; ++qg) {
    f32x4 lv = *(const f32x4*)&redL[w][qg * 16 + quad * 4];
    f32x4 li;
#pragma unroll
    for (int r = 0; r < 4; ++r) li[r] = 1.0f / lv[r];
#pragma unroll
    for (int nt = 0; nt < 4; ++nt)
#pragma unroll
      for (int r = 0; r < 4; ++r) {
        size_t tok = tokbase + q0 + w * 32 + qg * 16 + quad * 4 + r;
        O[tok * DM + hh * HD + nt * 16 + l15] = f2bu(Oacc[qg][nt][r] * li[r]);
      }
  }
}

// ---------------------------------------------------------------------------
// row-wise: s = base + d0 (+ d1); LN(s)*gamma+beta -> outf (fp32), outb (opt)
// ---------------------------------------------------------------------------
__global__ __launch_bounds__(256) void ln_res(
    const float* __restrict__ base, const float* __restrict__ d0,
    const float* __restrict__ d1,
    const float* __restrict__ gamma, const float* __restrict__ beta,
    float* __restrict__ outf, unsigned short* __restrict__ outb) {
  __shared__ float red[8];
  const int row = blockIdx.x, tid = threadIdx.x;
  const size_t rb = (size_t)row * DM;
  float4 xv = ((const float4*)(base + rb))[tid];
  float4 dv = ((const float4*)(d0 + rb))[tid];
  float s0 = xv.x + dv.x, s1 = xv.y + dv.y, s2 = xv.z + dv.z, s3 = xv.w + dv.w;
  if (d1) {
    float4 ev = ((const float4*)(d1 + rb))[tid];
    s0 += ev.x; s1 += ev.y; s2 += ev.z; s3 += ev.w;
  }
  float t = s0 + s1 + s2 + s3;
#pragma unroll
  for (int m = 1; m < 64; m <<= 1) t += __shfl_xor(t, m);
  if ((tid & 63) == 0) red[tid >> 6] = t;
  __syncthreads();
  float mu = (red[0] + red[1] + red[2] + red[3]) * (1.0f / DM);
  float dd0 = s0 - mu, dd1 = s1 - mu, dd2 = s2 - mu, dd3 = s3 - mu;
  float v = dd0 * dd0 + dd1 * dd1 + dd2 * dd2 + dd3 * dd3;
#pragma unroll
  for (int m = 1; m < 64; m <<= 1) v += __shfl_xor(v, m);
  if ((tid & 63) == 0) red[4 + (tid >> 6)] = v;
  __syncthreads();
  float var = (red[4] + red[5] + red[6] + red[7]) * (1.0f / DM);
  float rs = rsqrtf(var + 1e-5f);
  float4 gv = ((const float4*)gamma)[tid];
  float4 bv = ((const float4*)beta)[tid];
  float o0 = dd0 * rs * gv.x + bv.x;
  float o1 = dd1 * rs * gv.y + bv.y;
  float o2 = dd2 * rs * gv.z + bv.z;
  float o3 = dd3 * rs * gv.w + bv.w;
  float4 ov = {o0, o1, o2, o3};
  ((float4*)(outf + rb))[tid] = ov;
  if (outb) {
    u16x4 ob = {f2bu(o0), f2bu(o1), f2bu(o2), f2bu(o3)};
    ((u16x4*)(outb + rb))[tid] = ob;
  }
}

// ---------------------------------------------------------------------------
extern "C" void kernel_launch(void* const* d_in, const int* in_sizes, int n_in,
                              void* d_out, int out_size, void* d_ws, size_t ws_size,
                              hipStream_t stream) {
  const float* x   = (const float*)d_in[0];
  const float* Wq  = (const float*)d_in[1];  const float* bq  = (const float*)d_in[2];
  const float* Wk  = (const float*)d_in[3];  const float* bk  = (const float*)d_in[4];
  const float* Wv  = (const float*)d_in[5];  const float* bvv = (const float*)d_in[6];
  const float* Wo  = (const float*)d_in[7];  const float* bo  = (const float*)d_in[8];
  const float* W1  = (const float*)d_in[9];  const float* b1  = (const float*)d_in[10];
  const float* W2  = (const float*)d_in[11]; const float* b2  = (const float*)d_in[12];
  const float* g1  = (const float*)d_in[13]; const float* be1 = (const float*)d_in[14];
  const float* g2  = (const float*)d_in[15]; const float* be2 = (const float*)d_in[16];

  char* ws = (char*)d_ws;
  const size_t MB = 1ull << 20;
  unsigned short* xb    = (unsigned short*)(ws + 0 * MB);    // 16MB (later hb/ffo2 alias)
  unsigned short* wqkvT = (unsigned short*)(ws + 16 * MB);   // 6MB  [3072][1024]
  unsigned short* woT   = (unsigned short*)(ws + 22 * MB);   // 2MB
  unsigned short* w1T   = (unsigned short*)(ws + 24 * MB);   // 8MB
  unsigned short* w2T   = (unsigned short*)(ws + 32 * MB);   // 8MB
  unsigned short* Qb    = (unsigned short*)(ws + 40 * MB);   // 16MB
  unsigned short* Kb    = (unsigned short*)(ws + 56 * MB);   // 16MB
  unsigned short* Vtg   = (unsigned short*)(ws + 72 * MB);   // 32MB [(b,h,d)][s]
  unsigned short* aO    = (unsigned short*)(ws + 104 * MB);  // 16MB
  float*          prj   = (float*)(ws + 120 * MB);           // 32MB fp32
  float*          prj2  = (float*)(ws + 40 * MB);            // 32MB alias Qb/Kb (dead post-attn)
  float*          h     = (float*)(ws + 152 * MB);           // 32MB fp32
  unsigned short* hb    = (unsigned short*)(ws + 0 * MB);    // alias xb (dead)
  unsigned short* ffm   = (unsigned short*)(ws + 40 * MB);   // 64MB alias Qb..Vtg (post-LN1)
  float*          ffo   = (float*)(ws + 104 * MB);           // 32MB alias aO+prj
  float*          ffo2  = (float*)(ws + 0 * MB);             // 32MB alias xb/hb (dead by FF2)
  (void)ws_size; (void)in_sizes; (void)n_in; (void)out_size;

  // prep: cast x; weight transposes (B^T bf16); Wq/Wk/Wv stacked -> wqkvT
  cast_bf16<<<TOK * DM / 4 / 256, 256, 0, stream>>>(x, xb, TOK * DM / 4);
  transpose_cast4<<<dim3(DM / 32, DM / 32, 4), dim3(32, 8), 0, stream>>>(
      Wq, Wk, Wv, Wo, wqkvT, wqkvT + 1024 * 1024, wqkvT + 2048 * 1024, woT);
  transpose_cast<<<dim3(DFF / 32, DM / 32), dim3(32, 8), 0, stream>>>(W1, w1T, DM, DFF);
  transpose_cast<<<dim3(DM / 32, DFF / 32), dim3(32, 8), 0, stream>>>(W2, w2T, DFF, DM);

  // fused QKV projection (Q scaled for exp2-domain softmax; V transposed)
  gemm_qkv256<<<dim3(3 * DM / 256, TOK / 256), 512, 0, stream>>>(
      xb, wqkvT, bq, bk, bvv, Qb, Kb, Vtg);

  // attention
  attn_kernel<<<dim3(SEQ / 128, BATCH * NH), 256, 0, stream>>>(Qb, Kb, Vtg, aO);

  // output projection, split-K x2 (fills 256 blocks; fp32 partials)
  gemm256<<<dim3(DM / 256, TOK / 256, 2), 512, 0, stream>>>(
      aO, DM, woT, DM, DM / 2, bo, prj, prj2, DM, 1.0f, 0, 1);
  // LN1: h = LN(x + prj + prj2) -> fp32 h + bf16 hb
  ln_res<<<TOK, 256, 0, stream>>>(x, prj, prj2, g1, be1, h, hb);

  // FF1: relu(hb @ W1 + b1) -> bf16 ffm
  gemm256<<<dim3(DFF / 256, TOK / 256, 1), 512, 0, stream>>>(
      hb, DM, w1T, DM, DM, b1, ffm, nullptr, DFF, 1.0f, 1, 0);
  // FF2 split-K (z=0: k[0,2048) + bias -> ffo; z=1: k[2048,4096) -> ffo2)
  gemm256<<<dim3(DM / 256, TOK / 256, 2), 512, 0, stream>>>(
      ffm, DFF, w2T, DFF, DFF / 2, b2, ffo, ffo2, DM, 1.0f, 0, 1);

  // LN2 -> d_out (fp32): LN(h + ffo + ffo2)
  ln_res<<<TOK, 256, 0, stream>>>(h, ffo, ffo2, g2, be2, (float*)d_out, nullptr);
}

// Round 5
// 587.722 us; speedup vs baseline: 1.0363x; 1.0363x over previous
//
#include <hip/hip_runtime.h>
#include <hip/hip_bf16.h>

// ---------------------------------------------------------------------------
// EncoderLayer on MI355X (gfx950), round 10 (= R9 resubmit; R9 bench was an
// infra failure — container acquisition, kernel never executed).
// GEMMs: faithful m97-structure port. 128x128 tile, BK=32, 256 thr / 4 waves
// (wave tile 64x64 = 4x4 mfma_16x16x32 frags), LINEAR LDS (16KB), single
// buffer, two __syncthreads per K-step, global_load_lds(16B) x4. Latency
// hiding via 2-3 blocks/CU (TLP) instead of hand-rolled pipelining (R6-R8
// all 1 block/CU, latency-bound at 21-26% MfmaUtil).
// Attention / LN / prep unchanged. No split-K (all grids >= 512 blocks).
// ---------------------------------------------------------------------------

#define DM    1024
#define DFF   4096
#define NH    16
#define HD    64
#define BATCH 4
#define SEQ   2048
#define TOK   (BATCH * SEQ)   // 8192

typedef __attribute__((ext_vector_type(8))) __bf16 bf16x8;
typedef __attribute__((ext_vector_type(4))) float f32x4;
typedef __attribute__((ext_vector_type(4))) unsigned short u16x4;

typedef const __attribute__((address_space(1))) unsigned int* gas1_t;
typedef __attribute__((address_space(3))) unsigned int* las3_t;

__device__ __forceinline__ void gl_lds16(const void* g, void* l) {
  // async global->LDS, 16B per lane; LDS dest = wave-uniform base + lane*16
  __builtin_amdgcn_global_load_lds((gas1_t)g, (las3_t)l, 16, 0, 0);
}

__device__ __forceinline__ unsigned short f2bu(float x) {
  return __builtin_bit_cast(unsigned short, __float2bfloat16(x));
}

// pack hi16(a),hi16(b) -> (b | a<<16): bf16 truncation of two floats, 1 instr
__device__ __forceinline__ unsigned pk_bf16_trunc(float hi, float lo) {
  return __builtin_amdgcn_perm(__builtin_bit_cast(unsigned, hi),
                               __builtin_bit_cast(unsigned, lo), 0x07060302u);
}

// ---------------------------------------------------------------------------
// cast fp32 -> bf16 (vectorized x4)
// ---------------------------------------------------------------------------
__global__ __launch_bounds__(256) void cast_bf16(
    const float* __restrict__ in, unsigned short* __restrict__ out, int n4) {
  int i = blockIdx.x * 256 + threadIdx.x;
  if (i >= n4) return;
  float4 v = ((const float4*)in)[i];
  u16x4 o = {f2bu(v.x), f2bu(v.y), f2bu(v.z), f2bu(v.w)};
  ((u16x4*)out)[i] = o;
}

// ---------------------------------------------------------------------------
// out[n][k] = bf16(in[k][n])   (LDS-tiled transpose, block (32,8))
// ---------------------------------------------------------------------------
__global__ __launch_bounds__(256) void transpose_cast(
    const float* __restrict__ in, unsigned short* __restrict__ out, int K, int N) {
  __shared__ float tile[32][33];
  int n0 = blockIdx.x * 32, k0 = blockIdx.y * 32;
  int tx = threadIdx.x, ty = threadIdx.y;
#pragma unroll
  for (int i = 0; i < 4; ++i)
    tile[ty + 8 * i][tx] = in[(size_t)(k0 + ty + 8 * i) * N + n0 + tx];
  __syncthreads();
#pragma unroll
  for (int i = 0; i < 4; ++i)
    out[(size_t)(n0 + ty + 8 * i) * K + k0 + tx] = f2bu(tile[tx][ty + 8 * i]);
}

// 4 square (1024x1024) weight transposes in one launch (z selects matrix)
__global__ __launch_bounds__(256) void transpose_cast4(
    const float* __restrict__ A0, const float* __restrict__ A1,
    const float* __restrict__ A2, const float* __restrict__ A3,
    unsigned short* __restrict__ O0, unsigned short* __restrict__ O1,
    unsigned short* __restrict__ O2, unsigned short* __restrict__ O3) {
  __shared__ float tile[32][33];
  const float* in; unsigned short* out;
  switch (blockIdx.z) {
    case 0: in = A0; out = O0; break;
    case 1: in = A1; out = O1; break;
    case 2: in = A2; out = O2; break;
    default: in = A3; out = O3; break;
  }
  int n0 = blockIdx.x * 32, k0 = blockIdx.y * 32;
  int tx = threadIdx.x, ty = threadIdx.y;
#pragma unroll
  for (int i = 0; i < 4; ++i)
    tile[ty + 8 * i][tx] = in[(size_t)(k0 + ty + 8 * i) * DM + n0 + tx];
  __syncthreads();
#pragma unroll
  for (int i = 0; i < 4; ++i)
    out[(size_t)(n0 + ty + 8 * i) * DM + k0 + tx] = f2bu(tile[tx][ty + 8 * i]);
}

// ---------------------------------------------------------------------------
// m97-structure mainloop: 128x128 tile, BK=32, 4 waves 2x2 (wave 64x64).
// LDS: As,Bs = [128 rows][32 k] bf16 linear (8KB each). Per K-step:
//   stage 4 x gl_lds16 (A:2, B:2) -> __syncthreads (drains vmcnt+lgkm)
//   -> 8 ds_read_b128 frags -> 16 mfma_16x16x32 -> __syncthreads.
// Latency hidden by 2-3 independent blocks/CU, not intra-block pipelining.
// ---------------------------------------------------------------------------
__device__ __forceinline__ void mainloop128(
    const unsigned short* __restrict__ A, int lda,
    const unsigned short* __restrict__ Bt, int ldb, int Kl,
    int m0, int n0, unsigned short* As, unsigned short* Bs,
    f32x4 acc[4][4]) {
  const int tid = threadIdx.x, lane = tid & 63, w = tid >> 6;
  const int l15 = lane & 15, quad = lane >> 4;
  const int wr = w >> 1, wc = w & 1;

  // staging: instr i, granule g = i*256 + tid; row = g>>2, 16B-chunk = g&3
  const unsigned short* pa[2];
  const unsigned short* pb[2];
#pragma unroll
  for (int i = 0; i < 2; ++i) {
    const int g = i * 256 + tid;
    const int row = g >> 2, ch = (g & 3) * 8;
    pa[i] = A + (size_t)(m0 + row) * lda + ch;
    pb[i] = Bt + (size_t)(n0 + row) * ldb + ch;
  }

  for (int kb = 0; kb < Kl; kb += 32) {
#pragma unroll
    for (int i = 0; i < 2; ++i) {
      gl_lds16(pa[i], (char*)As + i * 4096 + w * 1024);
      gl_lds16(pb[i], (char*)Bs + i * 4096 + w * 1024);
      pa[i] += 32;
      pb[i] += 32;
    }
    __syncthreads();  // drains vmcnt (gl_lds) before reads

    bf16x8 aF[4], bF[4];
#pragma unroll
    for (int m = 0; m < 4; ++m)
      aF[m] = *(const bf16x8*)((const char*)As +
                               (wr * 64 + m * 16 + l15) * 64 + quad * 16);
#pragma unroll
    for (int n = 0; n < 4; ++n)
      bF[n] = *(const bf16x8*)((const char*)Bs +
                               (wc * 64 + n * 16 + l15) * 64 + quad * 16);
#pragma unroll
    for (int m = 0; m < 4; ++m)
#pragma unroll
      for (int n = 0; n < 4; ++n)
        acc[m][n] = __builtin_amdgcn_mfma_f32_16x16x32_bf16(
            aF[m], bF[n], acc[m][n], 0, 0, 0);
    __syncthreads();  // protect LDS from next-iter staging
  }
}

// C/D layout (16x16): col = lane&15, row = (lane>>4)*4 + reg
// acc[m][n]: rows m0+wr*64+m*16, cols n0+wc*64+n*16

// XCD-aware block swizzle: blocks with equal (lin%8) land on one XCD; give
// each XCD a contiguous chunk. Requires gridDim.x*gridDim.y % 8 == 0.
__device__ __forceinline__ void xcd_swizzle(int& bx, int& by) {
  const int gx = gridDim.x, nxy = gx * gridDim.y;
  int lin = by * gx + bx;
  lin = (lin & 7) * (nxy >> 3) + (lin >> 3);
  bx = lin % gx;
  by = lin / gx;
}

// ---------------------------------------------------------------------------
// Generic C[M,N] = epi(A @ Bt^T + bias): relu flag, fp32/bf16 row-major out.
// ---------------------------------------------------------------------------
__global__ __launch_bounds__(256) void gemm128(
    const unsigned short* __restrict__ A, int lda,
    const unsigned short* __restrict__ Bt, int ldb, int Kl,
    const float* __restrict__ bias, void* __restrict__ Cout,
    int N, float alpha, int relu, int ofp32) {
  __shared__ unsigned short As[128 * 32];
  __shared__ unsigned short Bs[128 * 32];
  const int tid = threadIdx.x, lane = tid & 63, w = tid >> 6;
  const int l15 = lane & 15, quad = lane >> 4;
  const int wr = w >> 1, wc = w & 1;
  int bx = blockIdx.x, by = blockIdx.y;
  xcd_swizzle(bx, by);
  const int m0 = by * 128, n0 = bx * 128;

  f32x4 acc[4][4];
#pragma unroll
  for (int m = 0; m < 4; ++m)
#pragma unroll
    for (int n = 0; n < 4; ++n) acc[m][n] = {0.f, 0.f, 0.f, 0.f};

  mainloop128(A, lda, Bt, ldb, Kl, m0, n0, As, Bs, acc);

#pragma unroll
  for (int n = 0; n < 4; ++n) {
    const int col = n0 + wc * 64 + n * 16 + l15;
    const float bvv = bias[col];
#pragma unroll
    for (int m = 0; m < 4; ++m) {
      const int rbase = m0 + wr * 64 + m * 16 + quad * 4;
#pragma unroll
      for (int r = 0; r < 4; ++r) {
        float val = alpha * (acc[m][n][r] + bvv);
        if (relu) val = fmaxf(val, 0.f);
        size_t idx = (size_t)(rbase + r) * N + col;
        if (ofp32) ((float*)Cout)[idx] = val;
        else ((unsigned short*)Cout)[idx] = f2bu(val);
      }
    }
  }
}

// ---------------------------------------------------------------------------
// Fused QKV gemm (128x128 tiles). N=3072: region 0: Q * QSCALE -> Qb;
// 1: K -> Kb; 2: V -> Vtg transposed per head [(b*16+h)*64+d][s].
// ---------------------------------------------------------------------------
#define QSCALE 0.18033688f  // (1/sqrt(64)) * log2(e): softmax runs in exp2 domain

__global__ __launch_bounds__(256) void gemm_qkv128(
    const unsigned short* __restrict__ A, const unsigned short* __restrict__ Bt,
    const float* __restrict__ bq, const float* __restrict__ bk,
    const float* __restrict__ bv,
    unsigned short* __restrict__ Qb, unsigned short* __restrict__ Kb,
    unsigned short* __restrict__ Vtg) {
  __shared__ unsigned short As[128 * 32];
  __shared__ unsigned short Bs[128 * 32];
  const int tid = threadIdx.x, lane = tid & 63, w = tid >> 6;
  const int l15 = lane & 15, quad = lane >> 4;
  const int wr = w >> 1, wc = w & 1;
  int bx = blockIdx.x, by = blockIdx.y;
  xcd_swizzle(bx, by);
  const int m0 = by * 128, n0 = bx * 128;

  f32x4 acc[4][4];
#pragma unroll
  for (int m = 0; m < 4; ++m)
#pragma unroll
    for (int n = 0; n < 4; ++n) acc[m][n] = {0.f, 0.f, 0.f, 0.f};

  mainloop128(A, DM, Bt, DM, DM, m0, n0, As, Bs, acc);

  const int region = n0 >> 10;  // 0=Q 1=K 2=V (128-tiles never straddle)
  if (region < 2) {
    unsigned short* Out = region ? Kb : Qb;
    const float* bias = region ? bk : bq;
    const float alpha = region ? 1.0f : QSCALE;
#pragma unroll
    for (int n = 0; n < 4; ++n) {
      const int col = (n0 & 1023) + wc * 64 + n * 16 + l15;
      const float bvv = bias[col];
#pragma unroll
      for (int m = 0; m < 4; ++m) {
        const int rbase = m0 + wr * 64 + m * 16 + quad * 4;
#pragma unroll
        for (int r = 0; r < 4; ++r)
          Out[(size_t)(rbase + r) * DM + col] =
              f2bu(alpha * (acc[m][n][r] + bvv));
      }
    }
  } else {
#pragma unroll
    for (int n = 0; n < 4; ++n) {
      const int col = (n0 & 1023) + wc * 64 + n * 16 + l15;  // d_model idx
      const float bvv = bv[col];
      const int hh = col >> 6, dl = col & 63;
#pragma unroll
      for (int m = 0; m < 4; ++m) {
        const int sbase = m0 + wr * 64 + m * 16 + quad * 4;  // mult of 4
        const int b_ = sbase >> 11, s0 = sbase & 2047;
        u16x4 pk;
#pragma unroll
        for (int r = 0; r < 4; ++r) pk[r] = f2bu(acc[m][n][r] + bvv);
        *(u16x4*)(Vtg + ((size_t)((b_ * NH + hh) * HD + dl)) * SEQ + s0) = pk;
      }
    }
  }
}

// ---------------------------------------------------------------------------
// Flash attention, S^T formulation, BQ=128, NO-max exp2 softmax. (unchanged)
// ---------------------------------------------------------------------------
__global__ __launch_bounds__(256) void attn_kernel(
    const unsigned short* __restrict__ Q, const unsigned short* __restrict__ K,
    const unsigned short* __restrict__ Vtg, unsigned short* __restrict__ O) {
  __shared__ unsigned short Kt[2][64 * 64];   // [kv][d] swizzled, 8KB x2
  __shared__ unsigned short Vt[2][64 * 64];   // [d][kv] swizzled, 8KB x2
  __shared__ unsigned short Pt[4][32 * 64];   // per-wave [q][kv], 4KB x4
  __shared__ __align__(16) float redL[4][32];

  const int tid = threadIdx.x, lane = tid & 63, w = tid >> 6;
  const int l15 = lane & 15, quad = lane >> 4;
  const int q0 = blockIdx.x * 128;
  const int bh = blockIdx.y, b = bh >> 4, hh = bh & 15;
  const size_t tokbase = (size_t)b * SEQ;

  bf16x8 qf[2][2];
#pragma unroll
  for (int qg = 0; qg < 2; ++qg)
#pragma unroll
    for (int kk = 0; kk < 2; ++kk)
      qf[qg][kk] = *(const bf16x8*)(Q +
          (tokbase + q0 + w * 32 + qg * 16 + l15) * DM + hh * HD + kk * 32 + quad * 8);

  float l_run[2] = {0.f, 0.f};
  f32x4 Oacc[2][4];
#pragma unroll
  for (int qg = 0; qg < 2; ++qg)
#pragma unroll
    for (int nt = 0; nt < 4; ++nt) Oacc[qg][nt] = {0.f, 0.f, 0.f, 0.f};

  char* ptw = (char*)&Pt[w][0];

  int rowS[2], csrcS[2];
#pragma unroll
  for (int i = 0; i < 2; ++i) {
    int f = (i * 4 + w) * 64 + lane;
    rowS[i] = f >> 3;
    csrcS[i] = ((f & 7) ^ (rowS[i] & 7)) * 8;
  }
  const unsigned short* kg[2];
  const unsigned short* vg[2];
  char* ldsK[2][2]; char* ldsV[2][2];
#pragma unroll
  for (int i = 0; i < 2; ++i) {
    kg[i] = K + (tokbase + rowS[i]) * DM + hh * HD + csrcS[i];
    vg[i] = Vtg + ((size_t)bh * HD + rowS[i]) * SEQ + csrcS[i];
#pragma unroll
    for (int bb = 0; bb < 2; ++bb) {
      ldsK[bb][i] = (char*)Kt[bb] + (size_t)((i * 4 + w) * 1024);
      ldsV[bb][i] = (char*)Vt[bb] + (size_t)((i * 4 + w) * 1024);
    }
  }

#pragma unroll
  for (int i = 0; i < 2; ++i) {
    gl_lds16(kg[i], ldsK[0][i]);
    gl_lds16(vg[i], ldsV[0][i]);
    kg[i] += 64 * DM;
    vg[i] += 64;
  }

  for (int j = 0; j < SEQ / 64; ++j) {
    const int buf = j & 1;
    __syncthreads();
    if (j + 1 < SEQ / 64) {
#pragma unroll
      for (int i = 0; i < 2; ++i) {
        gl_lds16(kg[i], ldsK[buf ^ 1][i]);
        gl_lds16(vg[i], ldsV[buf ^ 1][i]);
        kg[i] += 64 * DM;
        vg[i] += 64;
      }
    }

    const char* ktb = (const char*)Kt[buf];
    const char* vtb = (const char*)Vt[buf];

    f32x4 S[2][4];
#pragma unroll
    for (int qg = 0; qg < 2; ++qg)
#pragma unroll
      for (int mt = 0; mt < 4; ++mt) S[qg][mt] = {0.f, 0.f, 0.f, 0.f};
#pragma unroll
    for (int kk = 0; kk < 2; ++kk) {
#pragma unroll
      for (int mt = 0; mt < 4; ++mt) {
        bf16x8 aK = *(const bf16x8*)(ktb + (mt * 16 + l15) * 128 +
                                     (((kk * 4 + quad) ^ (l15 & 7)) * 16));
        S[0][mt] = __builtin_amdgcn_mfma_f32_16x16x32_bf16(aK, qf[0][kk], S[0][mt], 0, 0, 0);
        S[1][mt] = __builtin_amdgcn_mfma_f32_16x16x32_bf16(aK, qf[1][kk], S[1][mt], 0, 0, 0);
      }
    }

#pragma unroll
    for (int qg = 0; qg < 2; ++qg) {
      float rs = 0.f;
#pragma unroll
      for (int mt = 0; mt < 4; ++mt) {
        float p0 = __builtin_amdgcn_exp2f(S[qg][mt][0]);
        float p1 = __builtin_amdgcn_exp2f(S[qg][mt][1]);
        float p2 = __builtin_amdgcn_exp2f(S[qg][mt][2]);
        float p3 = __builtin_amdgcn_exp2f(S[qg][mt][3]);
        rs += (p0 + p1) + (p2 + p3);
        uint2 pk = {pk_bf16_trunc(p1, p0), pk_bf16_trunc(p3, p2)};
        *(uint2*)(ptw + (qg * 16 + l15) * 128 +
                  (((mt * 2 + (quad >> 1)) ^ (l15 & 7)) * 16 + (quad & 1) * 8)) = pk;
      }
      l_run[qg] += rs;
    }

#pragma unroll
    for (int kk = 0; kk < 2; ++kk) {
      bf16x8 aP[2];
#pragma unroll
      for (int qg = 0; qg < 2; ++qg)
        aP[qg] = *(const bf16x8*)(ptw + (qg * 16 + l15) * 128 +
                                  (((kk * 4 + quad) ^ (l15 & 7)) * 16));
#pragma unroll
      for (int nt = 0; nt < 4; ++nt) {
        bf16x8 bV = *(const bf16x8*)(vtb + (nt * 16 + l15) * 128 +
                                     (((kk * 4 + quad) ^ (l15 & 7)) * 16));
        Oacc[0][nt] = __builtin_amdgcn_mfma_f32_16x16x32_bf16(aP[0], bV, Oacc[0][nt], 0, 0, 0);
        Oacc[1][nt] = __builtin_amdgcn_mfma_f32_16x16x32_bf16(aP[1], bV, Oacc[1][nt], 0, 0, 0);
      }
    }
  }

#pragma unroll
  for (int qg = 0; qg < 2; ++qg) {
    l_run[qg] += __shfl_xor(l_run[qg], 16);
    l_run[qg] += __shfl_xor(l_run[qg], 32);
    if (lane < 16) redL[w][qg * 16 + l15] = l_run[qg];
  }
#pragma unroll
  for (int qg = 0; qg < 2; ++qg) {
    f32x4 lv = *(const f32x4*)&redL[w][qg * 16 + quad * 4];
    f32x4 li;
#pragma unroll
    for (int r = 0; r < 4; ++r) li[r] = 1.0f / lv[r];
#pragma unroll
    for (int nt = 0; nt < 4; ++nt)
#pragma unroll
      for (int r = 0; r < 4; ++r) {
        size_t tok = tokbase + q0 + w * 32 + qg * 16 + quad * 4 + r;
        O[tok * DM + hh * HD + nt * 16 + l15] = f2bu(Oacc[qg][nt][r] * li[r]);
      }
  }
}

// ---------------------------------------------------------------------------
// row-wise: s = base + d0 (+ d1); LN(s)*gamma+beta -> outf (fp32), outb (opt)
// ---------------------------------------------------------------------------
__global__ __launch_bounds__(256) void ln_res(
    const float* __restrict__ base, const float* __restrict__ d0,
    const float* __restrict__ d1,
    const float* __restrict__ gamma, const float* __restrict__ beta,
    float* __restrict__ outf, unsigned short* __restrict__ outb) {
  __shared__ float red[8];
  const int row = blockIdx.x, tid = threadIdx.x;
  const size_t rb = (size_t)row * DM;
  float4 xv = ((const float4*)(base + rb))[tid];
  float4 dv = ((const float4*)(d0 + rb))[tid];
  float s0 = xv.x + dv.x, s1 = xv.y + dv.y, s2 = xv.z + dv.z, s3 = xv.w + dv.w;
  if (d1) {
    float4 ev = ((const float4*)(d1 + rb))[tid];
    s0 += ev.x; s1 += ev.y; s2 += ev.z; s3 += ev.w;
  }
  float t = s0 + s1 + s2 + s3;
#pragma unroll
  for (int m = 1; m < 64; m <<= 1) t += __shfl_xor(t, m);
  if ((tid & 63) == 0) red[tid >> 6] = t;
  __syncthreads();
  float mu = (red[0] + red[1] + red[2] + red[3]) * (1.0f / DM);
  float dd0 = s0 - mu, dd1 = s1 - mu, dd2 = s2 - mu, dd3 = s3 - mu;
  float v = dd0 * dd0 + dd1 * dd1 + dd2 * dd2 + dd3 * dd3;
#pragma unroll
  for (int m = 1; m < 64; m <<= 1) v += __shfl_xor(v, m);
  if ((tid & 63) == 0) red[4 + (tid >> 6)] = v;
  __syncthreads();
  float var = (red[4] + red[5] + red[6] + red[7]) * (1.0f / DM);
  float rs = rsqrtf(var + 1e-5f);
  float4 gv = ((const float4*)gamma)[tid];
  float4 bv = ((const float4*)beta)[tid];
  float o0 = dd0 * rs * gv.x + bv.x;
  float o1 = dd1 * rs * gv.y + bv.y;
  float o2 = dd2 * rs * gv.z + bv.z;
  float o3 = dd3 * rs * gv.w + bv.w;
  float4 ov = {o0, o1, o2, o3};
  ((float4*)(outf + rb))[tid] = ov;
  if (outb) {
    u16x4 ob = {f2bu(o0), f2bu(o1), f2bu(o2), f2bu(o3)};
    ((u16x4*)(outb + rb))[tid] = ob;
  }
}

// ---------------------------------------------------------------------------
extern "C" void kernel_launch(void* const* d_in, const int* in_sizes, int n_in,
                              void* d_out, int out_size, void* d_ws, size_t ws_size,
                              hipStream_t stream) {
  const float* x   = (const float*)d_in[0];
  const float* Wq  = (const float*)d_in[1];  const float* bq  = (const float*)d_in[2];
  const float* Wk  = (const float*)d_in[3];  const float* bk  = (const float*)d_in[4];
  const float* Wv  = (const float*)d_in[5];  const float* bvv = (const float*)d_in[6];
  const float* Wo  = (const float*)d_in[7];  const float* bo  = (const float*)d_in[8];
  const float* W1  = (const float*)d_in[9];  const float* b1  = (const float*)d_in[10];
  const float* W2  = (const float*)d_in[11]; const float* b2  = (const float*)d_in[12];
  const float* g1  = (const float*)d_in[13]; const float* be1 = (const float*)d_in[14];
  const float* g2  = (const float*)d_in[15]; const float* be2 = (const float*)d_in[16];

  char* ws = (char*)d_ws;
  const size_t MB = 1ull << 20;
  unsigned short* xb    = (unsigned short*)(ws + 0 * MB);    // 16MB (later hb alias)
  unsigned short* wqkvT = (unsigned short*)(ws + 16 * MB);   // 6MB  [3072][1024]
  unsigned short* woT   = (unsigned short*)(ws + 22 * MB);   // 2MB
  unsigned short* w1T   = (unsigned short*)(ws + 24 * MB);   // 8MB
  unsigned short* w2T   = (unsigned short*)(ws + 32 * MB);   // 8MB
  unsigned short* Qb    = (unsigned short*)(ws + 40 * MB);   // 16MB
  unsigned short* Kb    = (unsigned short*)(ws + 56 * MB);   // 16MB
  unsigned short* Vtg   = (unsigned short*)(ws + 72 * MB);   // 32MB [(b,h,d)][s]
  unsigned short* aO    = (unsigned short*)(ws + 104 * MB);  // 16MB
  float*          prj   = (float*)(ws + 120 * MB);           // 32MB fp32
  float*          h     = (float*)(ws + 152 * MB);           // 32MB fp32
  unsigned short* hb    = (unsigned short*)(ws + 0 * MB);    // alias xb (dead)
  unsigned short* ffm   = (unsigned short*)(ws + 40 * MB);   // 64MB alias Qb..Vtg
  float*          ffo   = (float*)(ws + 104 * MB);           // 32MB alias aO+prj
  (void)ws_size; (void)in_sizes; (void)n_in; (void)out_size;

  // prep: cast x; weight transposes (B^T bf16); Wq/Wk/Wv stacked -> wqkvT
  cast_bf16<<<TOK * DM / 4 / 256, 256, 0, stream>>>(x, xb, TOK * DM / 4);
  transpose_cast4<<<dim3(DM / 32, DM / 32, 4), dim3(32, 8), 0, stream>>>(
      Wq, Wk, Wv, Wo, wqkvT, wqkvT + 1024 * 1024, wqkvT + 2048 * 1024, woT);
  transpose_cast<<<dim3(DFF / 32, DM / 32), dim3(32, 8), 0, stream>>>(W1, w1T, DM, DFF);
  transpose_cast<<<dim3(DM / 32, DFF / 32), dim3(32, 8), 0, stream>>>(W2, w2T, DFF, DM);

  // fused QKV projection (Q scaled for exp2-domain softmax; V transposed)
  gemm_qkv128<<<dim3(3 * DM / 128, TOK / 128), 256, 0, stream>>>(
      xb, wqkvT, bq, bk, bvv, Qb, Kb, Vtg);

  // attention
  attn_kernel<<<dim3(SEQ / 128, BATCH * NH), 256, 0, stream>>>(Qb, Kb, Vtg, aO);

  // output projection (fp32 out for residual precision)
  gemm128<<<dim3(DM / 128, TOK / 128), 256, 0, stream>>>(
      aO, DM, woT, DM, DM, bo, prj, DM, 1.0f, 0, 1);
  // LN1: h = LN(x + prj) -> fp32 h + bf16 hb
  ln_res<<<TOK, 256, 0, stream>>>(x, prj, nullptr, g1, be1, h, hb);

  // FF1: relu(hb @ W1 + b1) -> bf16 ffm
  gemm128<<<dim3(DFF / 128, TOK / 128), 256, 0, stream>>>(
      hb, DM, w1T, DM, DM, b1, ffm, DFF, 1.0f, 1, 0);
  // FF2
  gemm128<<<dim3(DM / 128, TOK / 128), 256, 0, stream>>>(
      ffm, DFF, w2T, DFF, DFF, b2, ffo, DM, 1.0f, 0, 1);

  // LN2 -> d_out (fp32): LN(h + ffo)
  ln_res<<<TOK, 256, 0, stream>>>(h, ffo, nullptr, g2, be2, (float*)d_out, nullptr);
}